// Round 10
// baseline (231.710 us; speedup 1.0000x reference)
//
#include <hip/hip_runtime.h>
#include <hip/hip_bf16.h>

typedef unsigned short u16;
typedef unsigned int u32;
typedef __attribute__((ext_vector_type(8))) short bf16x8;
typedef __attribute__((ext_vector_type(4))) float f32x4;
typedef __attribute__((ext_vector_type(16))) float f32x16;
typedef __attribute__((ext_vector_type(4))) unsigned short u16x4;
typedef __attribute__((ext_vector_type(4))) unsigned int u32x4;

#define SQ 4096
#define HQ 128
#define NCHUNK 144   // per batch: sum over qt2 of ceil((qt2+1)/4), chunk = 8 key-tiles

__device__ __forceinline__ u16 f2b(float f) {
  unsigned int u = __float_as_uint(f);
  unsigned int r = (u + 0x7fffu + ((u >> 16) & 1u)) >> 16;  // RNE bf16
  return (u16)r;
}

__device__ __forceinline__ u16 f2b_fast(float f) {
  __hip_bfloat16 h = __float2bfloat16(f);
  return __builtin_bit_cast(u16, h);
}

__device__ __forceinline__ float b2f(u16 v) {
  unsigned int u = ((unsigned int)v) << 16;
  return __uint_as_float(u);
}

__device__ __forceinline__ u32 cvtpk(float lo, float hi) {
  u32 r;
  asm("v_cvt_pk_bf16_f32 %0, %1, %2" : "=v"(r) : "v"(lo), "v"(hi));
  return r;
}

__device__ __forceinline__ void pswap(u32& a, u32& b) {
  asm("v_permlane32_swap_b32 %0, %1" : "+v"(a), "+v"(b));
}

__device__ __forceinline__ void gload_lds16(const u16* gsrc, u16* ldst) {
  __builtin_amdgcn_global_load_lds((const __attribute__((address_space(1))) void*)gsrc,
                                   (__attribute__((address_space(3))) void*)ldst, 16, 0, 0);
}

// Wt[z][n][k] = W_z[k][n]  (bf16, B^T layout for MFMA B-frags)
__global__ __launch_bounds__(256) void k_wt(const float* __restrict__ Wq, const float* __restrict__ Wk,
                                            const float* __restrict__ Wv, u16* __restrict__ wt) {
  int idx = blockIdx.x * 256 + threadIdx.x;
  int z = idx >> 17, r = idx & 131071, n = r >> 10, k = r & 1023;
  const float* W = (z == 0) ? Wq : (z == 1) ? Wk : Wv;
  wt[idx] = f2b(W[k * 128 + n]);
}

// Projection v3: no LDS, no barriers. Block = 32 x-rows x 384 cols, 8 waves
// (1m x 8n): all waves share the A rows (L1-served), B streams from L2-resident
// Wt. x f32 read directly and converted in-register. Compiler free-pipelines.
__global__ __launch_bounds__(512) void k_proj(const float* __restrict__ x, const u16* __restrict__ wt,
                                              u16* __restrict__ qb, u16* __restrict__ kb,
                                              u16* __restrict__ vt) {
  int blk = blockIdx.x;
  int t = threadIdx.x, w = t >> 6, lane = t & 63;
  int lr = lane & 15, lg = lane >> 4;
  int n0 = w * 48;

  f32x4 acc[2][3];
#pragma unroll
  for (int i = 0; i < 2; ++i)
#pragma unroll
    for (int j = 0; j < 3; ++j) acc[i][j] = (f32x4){0.f, 0.f, 0.f, 0.f};

  const float* xr = x + (long)(blk * 32 + lr) * 1024 + lg * 8;
  const u16* wb0 = wt + (long)(n0 + lr) * 1024 + lg * 8;

#pragma unroll 2
  for (int ks = 0; ks < 32; ++ks) {
    int k0 = ks * 32;
    bf16x8 af[2];
#pragma unroll
    for (int i = 0; i < 2; ++i) {
      const float* ap = xr + i * 16 * 1024 + k0;
      float4 a0 = *(const float4*)ap;
      float4 a1 = *(const float4*)(ap + 4);
      bf16x8 v;
      v[0] = (short)f2b_fast(a0.x); v[1] = (short)f2b_fast(a0.y);
      v[2] = (short)f2b_fast(a0.z); v[3] = (short)f2b_fast(a0.w);
      v[4] = (short)f2b_fast(a1.x); v[5] = (short)f2b_fast(a1.y);
      v[6] = (short)f2b_fast(a1.z); v[7] = (short)f2b_fast(a1.w);
      af[i] = v;
    }
    bf16x8 bfr[3];
#pragma unroll
    for (int j = 0; j < 3; ++j)
      bfr[j] = *(const bf16x8*)(wb0 + (long)j * 16 * 1024 + k0);
#pragma unroll
    for (int i = 0; i < 2; ++i)
#pragma unroll
      for (int j = 0; j < 3; ++j)
        acc[i][j] = __builtin_amdgcn_mfma_f32_16x16x32_bf16(af[i], bfr[j], acc[i][j], 0, 0, 0);
  }

  // epilogue: C layout row=(lane>>4)*4+reg, col=lane&15
#pragma unroll
  for (int i = 0; i < 2; ++i)
#pragma unroll
    for (int j = 0; j < 3; ++j)
#pragma unroll
      for (int r = 0; r < 4; ++r) {
        int m = blk * 32 + i * 16 + lg * 4 + r;
        int col = n0 + j * 16 + lr;
        int z = col >> 7, cz = col & 127;
        u16 v = f2b(acc[i][j][r]);
        if (z == 0) qb[(long)m * 128 + cz] = v;
        else if (z == 1) kb[(long)m * 128 + cz] = v;
        else { int bb = m >> 12, sR = m & 4095; vt[(long)bb * 524288 + (long)cz * 4096 + sR] = v; }
      }
}

// flash attention v7: 4-wave blocks (256 thr), wave = 32 q-rows, KVBLK=64,
// 32x32x16 MFMAs. Swapped QK^T (S^T: col=q) -> P lane-local; PV B-frags built
// in-register via v_cvt_pk_bf16_f32 + v_permlane32_swap_b32 (T12) -> zero P
// LDS traffic. K swizzle ch^(row&15) (conflict-free), V ch^(row&7). Fixed-max
// softmax, per-lane l sum. Split-K chunks of 8 tiles (NCHUNK=144), bf16 partials.
__global__ __launch_bounds__(256) void k_attn(const u16* __restrict__ qb, const u16* __restrict__ kb,
                                              const u16* __restrict__ vt, const int* __restrict__ kmask,
                                              u16* __restrict__ po, float* __restrict__ pl) {
  const float SCALE_LOG2 = 0.08838834764831845f * 1.4426950408889634f;
  const float MFIX = 24.0f;
  int f = (NCHUNK - 1) - (int)blockIdx.x;  // long chunks first
  int b = blockIdx.y;
  int qt2 = 0, cum = 0;
  while (cum + ((qt2 + 4) >> 2) <= f) { cum += (qt2 + 4) >> 2; ++qt2; }
  int kc = f - cum;
  int ntile = 2 * qt2 + 2;
  int kt0 = kc * 8;
  int kt1 = min(kt0 + 8, ntile);

  int t = threadIdx.x, w = t >> 6, lane = t & 63;
  int lq = lane & 31, hh = lane >> 5;
  int qrow0 = qt2 * 128 + w * 32;
  const u16* K = kb + (long)b * SQ * HQ;
  const u16* V = vt + (long)b * HQ * SQ;   // V^T: [128][SQ]
  const int* msk = kmask + b * SQ;

  __shared__ __align__(16) u16 Kl[2][64 * 128];   // 2 x 16 KB
  __shared__ __align__(16) u16 Vl[2][128 * 64];   // 2 x 16 KB

  // Q B-frags (col=q=lane&31, k-elems (lane>>5)*8+e), 8 frags over d=128
  bf16x8 qf[8];
  {
    const u16* Qp = qb + (long)(b * SQ + qrow0 + lq) * HQ + hh * 8;
#pragma unroll
    for (int c = 0; c < 8; ++c) qf[c] = *(const bf16x8*)(Qp + c * 16);
  }

  f32x16 ot[4];
#pragma unroll
  for (int d = 0; d < 4; ++d) ot[d] = (f32x16)(0.f);
  float lsum = 0.f;

  // stage one 64-key tile: K 1024 chunks, V 1024 chunks; 4+4 per thread
  auto stage = [&](int bufi, int kb0) {
    const u16* Kg = K + (long)kb0 * HQ;
    const u16* Vg = V + kb0;
#pragma unroll
    for (int i = 0; i < 4; ++i) {
      int cg = w * 4 + i;                 // 0..15
      int idx = cg * 64 + lane;
      int row = idx >> 4, ch = idx & 15;  // K: 16 chunks per 256B row
      gload_lds16(Kg + row * HQ + ((ch ^ (row & 15)) << 3), &Kl[bufi][cg * 512]);
    }
#pragma unroll
    for (int i = 0; i < 4; ++i) {
      int cg = w * 4 + i;
      int idx = cg * 64 + lane;
      int row = idx >> 3, ch = idx & 7;   // V: 8 chunks per 128B row
      gload_lds16(Vg + (long)row * SQ + ((ch ^ (row & 7)) << 3), &Vl[bufi][cg * 512]);
    }
  };

  stage(0, kt0 * 64);
  __syncthreads();

  for (int kt = kt0; kt < kt1; ++kt) {
    int cur = (kt - kt0) & 1;
    int kb0 = kt * 64;
    if (kt + 1 < kt1) stage(cur ^ 1, kb0 + 64);

    if (kb0 <= qrow0 + 31) {               // wave-uniform: any valid keys?
      // ---- swapped QK^T: S^T[key][q], A=K-frag, B=Q-frag; 16 MFMAs 32x32x16
      f32x16 st[2];
#pragma unroll
      for (int kf = 0; kf < 2; ++kf) {
        f32x16 a = (f32x16)(0.f);
        int krow = kf * 32 + lq;
        const u16* Kp = &Kl[cur][krow * 128];
        int swz = krow & 15;
#pragma unroll
        for (int c = 0; c < 8; ++c) {
          bf16x8 ka = *(const bf16x8*)(Kp + (((c * 2 + hh) ^ swz) << 3));
          a = __builtin_amdgcn_mfma_f32_32x32x16_bf16(ka, qf[c], a, 0, 0, 0);
        }
        st[kf] = a;
      }
      // ---- softmax (fixed shift), all in-register; lane holds 32 keys of q=lq
      int mv = msk[kb0 + lane];
      bool allv = __all(mv != 0);
      bool needc = (kb0 + 63 > qrow0);
      int q = qrow0 + lq;
      float p[32];
#pragma unroll
      for (int kf = 0; kf < 2; ++kf)
#pragma unroll
        for (int j = 0; j < 16; ++j) {
          int keyl = kf * 32 + (j & 3) + 8 * (j >> 2) + 4 * hh;
          int key = kb0 + keyl;
          float pp = __builtin_exp2f(fmaf(st[kf][j], SCALE_LOG2, -MFIX));
          if (!allv) pp = (msk[key] != 0) ? pp : 0.f;
          if (needc) pp = (key <= q) ? pp : 0.f;
          p[kf * 16 + j] = pp;
          lsum += pp;
        }
      // ---- PV: B-frags from p via cvt_pk + permlane32_swap; A=V^T from LDS
#pragma unroll
      for (int kk = 0; kk < 4; ++kk) {
        int rb = (kk >> 1) * 16 + (kk & 1) * 8;
        u32 X = cvtpk(p[rb + 0], p[rb + 1]);
        u32 Z = cvtpk(p[rb + 2], p[rb + 3]);
        u32 Y = cvtpk(p[rb + 4], p[rb + 5]);
        u32 W2 = cvtpk(p[rb + 6], p[rb + 7]);
        pswap(X, Y);   // X: word0 (keys 0-1 / 8-9), Y: word2 (keys 4-5 / 12-13)
        pswap(Z, W2);  // Z: word1, W2: word3
        u32x4 pk; pk[0] = X; pk[1] = Z; pk[2] = Y; pk[3] = W2;
        bf16x8 pb = __builtin_bit_cast(bf16x8, pk);
#pragma unroll
        for (int d = 0; d < 4; ++d) {
          int vrow = d * 32 + lq;
          bf16x8 va = *(const bf16x8*)(&Vl[cur][vrow * 64 + (((kk * 2 + hh) ^ (vrow & 7)) << 3)]);
          ot[d] = __builtin_amdgcn_mfma_f32_32x32x16_bf16(va, pb, ot[d], 0, 0, 0);
        }
      }
    }
    __syncthreads();
  }

  // ---- write partials: O^T regs -> po[q][d] bf16; l via partner-half add
  lsum += __shfl_xor(lsum, 32);
  long pbi = (long)b * NCHUNK + f;
  u16* pob = po + pbi * 16384;  // [128][128] bf16
  int qloc = w * 32 + lq;
#pragma unroll
  for (int d = 0; d < 4; ++d)
#pragma unroll
    for (int g = 0; g < 4; ++g) {
      int d0 = d * 32 + 8 * g + 4 * hh;
      u16x4 vv;
      vv[0] = f2b_fast(ot[d][4 * g + 0]);
      vv[1] = f2b_fast(ot[d][4 * g + 1]);
      vv[2] = f2b_fast(ot[d][4 * g + 2]);
      vv[3] = f2b_fast(ot[d][4 * g + 3]);
      *(u16x4*)(pob + (long)qloc * 128 + d0) = vv;
    }
  if (hh == 0) pl[pbi * 128 + qloc] = lsum;
}

// merge: out[b, qt2*128+row, :] = sum_i po[i] / sum_i pl[i]
__global__ __launch_bounds__(256) void k_merge(const u16* __restrict__ po, const float* __restrict__ pl,
                                               float* __restrict__ out) {
  int qt2 = blockIdx.x, b = blockIdx.y;
  int nch = (qt2 + 4) >> 2;
  int pre = 0;
  for (int q = 0; q < qt2; ++q) pre += (q + 4) >> 2;
  long pbase = (long)b * NCHUNK + pre;
  int t = threadIdx.x;
  int row = t >> 1, c0 = (t & 1) * 64;
  float l = 0.f;
  for (int i = 0; i < nch; ++i) l += pl[(pbase + i) * 128 + row];
  float inv = 1.0f / l;
  const u16* p0 = po + pbase * 16384 + row * 128 + c0;
  float* orow = out + ((long)(b * SQ + qt2 * 128 + row)) * HQ + c0;
#pragma unroll
  for (int j = 0; j < 64; j += 4) {
    float acc0 = 0.f, acc1 = 0.f, acc2 = 0.f, acc3 = 0.f;
    for (int i = 0; i < nch; ++i) {
      u16x4 v = *(const u16x4*)(p0 + (long)i * 16384 + j);
      acc0 += b2f(v[0]); acc1 += b2f(v[1]); acc2 += b2f(v[2]); acc3 += b2f(v[3]);
    }
    float4 r = {acc0 * inv, acc1 * inv, acc2 * inv, acc3 * inv};
    *(float4*)(orow + j) = r;
  }
}

extern "C" void kernel_launch(void* const* d_in, const int* in_sizes, int n_in,
                              void* d_out, int out_size, void* d_ws, size_t ws_size,
                              hipStream_t stream) {
  const float* x  = (const float*)d_in[0];
  const float* Wq = (const float*)d_in[1];
  const float* Wk = (const float*)d_in[2];
  const float* Wv = (const float*)d_in[3];
  const int* kmask = (const int*)d_in[4];
  char* ws = (char*)d_ws;
  u16* wt = (u16*)(ws + 33554432);            // 768 KB: Wt (dead after k_proj)
  u16* qb = (u16*)(ws + 34340864);            // 4 MB: Q bf16
  u16* kb = (u16*)(ws + 38535168);            // 4 MB: K bf16
  u16* vt = (u16*)(ws + 42729472);            // 4 MB: V^T bf16 [4][128][4096]
  u16* po = (u16*)ws;                         // 18.9 MB partial O (bf16)
  float* pl = (float*)(ws + 33554432 - 2359296);  // 295 KB partial l (before wt... keep safe)
  float* out = (float*)d_out;
  // NOTE: pl placed at ws+31195136 (inside the po region tail, past used 144*4*32KB=18.9MB) — safe.

  k_wt<<<1536, 256, 0, stream>>>(Wq, Wk, Wv, wt);
  k_proj<<<512, 512, 0, stream>>>(x, wt, qb, kb, vt);
  k_attn<<<dim3(NCHUNK, 4), 256, 0, stream>>>(qb, kb, vt, kmask, po, pl);
  k_merge<<<dim3(32, 4), 256, 0, stream>>>(po, pl, out);
}

// Round 11
// 117.437 us; speedup vs baseline: 1.9731x; 1.9731x over previous
//
#include <hip/hip_runtime.h>
#include <hip/hip_bf16.h>

typedef unsigned short u16;
typedef __attribute__((ext_vector_type(8))) short bf16x8;
typedef __attribute__((ext_vector_type(4))) float f32x4;
typedef __attribute__((ext_vector_type(4))) unsigned short u16x4;

#define SQ 4096
#define HQ 128
#define NCHUNK 144   // per batch: sum over qt2 of ceil((qt2+1)/4), chunk = 8 key-tiles

__device__ __forceinline__ u16 f2b(float f) {
  unsigned int u = __float_as_uint(f);
  unsigned int r = (u + 0x7fffu + ((u >> 16) & 1u)) >> 16;  // RNE bf16
  return (u16)r;
}

__device__ __forceinline__ u16 f2b_fast(float f) {
  __hip_bfloat16 h = __float2bfloat16(f);
  return __builtin_bit_cast(u16, h);
}

__device__ __forceinline__ float b2f(u16 v) {
  unsigned int u = ((unsigned int)v) << 16;
  return __uint_as_float(u);
}

__device__ __forceinline__ void gload_lds16(const u16* gsrc, u16* ldst) {
  __builtin_amdgcn_global_load_lds((const __attribute__((address_space(1))) void*)gsrc,
                                   (__attribute__((address_space(3))) void*)ldst, 16, 0, 0);
}

// Wt[z][n][k] = W_z[k][n]  (bf16, B^T layout for MFMA B-frags)
__global__ __launch_bounds__(256) void k_wt(const float* __restrict__ Wq, const float* __restrict__ Wk,
                                            const float* __restrict__ Wv, u16* __restrict__ wt) {
  int idx = blockIdx.x * 256 + threadIdx.x;
  int z = idx >> 17, r = idx & 131071, n = r >> 10, k = r & 1023;
  const float* W = (z == 0) ? Wq : (z == 1) ? Wk : Wv;
  wt[idx] = f2b(W[k * 128 + n]);
}

// Fused conv+proj v4: block = 64 x-rows x 192 cols (N-split), grid (256,2),
// 512 thr (8 waves 2m x 4n). LDS 32KB -> 2-4 blocks/CU co-resident. x f32
// loaded with 3-deep prefetch (latency spans 3 iters), converted in-register,
// staged to swizzled LDS; W via global_load_lds (pre-swizzled source), dbuf.
__global__ __launch_bounds__(512, 4) void k_proj(const float* __restrict__ x, const u16* __restrict__ wt,
                                                 u16* __restrict__ qb, u16* __restrict__ kb,
                                                 u16* __restrict__ vt) {
  int mt = blockIdx.x, nh = blockIdx.y;
  int t = threadIdx.x;
  int w = t >> 6, lane = t & 63;
  int wm = w >> 2, wn = w & 3;
  int lr = lane & 15, lg = lane >> 4;

  __shared__ __align__(16) u16 xl[2][64 * 32];    // 2 x 4 KB
  __shared__ __align__(16) u16 wl[2][192 * 32];   // 2 x 12 KB

  int srow = t >> 3, sc8 = t & 7;                  // x: row 0..63, 4-f32 group 0..7
  const float* xg = x + (long)(mt * 64 + srow) * 1024 + sc8 * 4;
  int xch = ((sc8 >> 1) ^ ((srow >> 1) & 3));      // swizzled 16B chunk
  int xoff = srow * 32 + xch * 8 + (sc8 & 1) * 4;  // u16 offset within a buffer

  f32x4 acc[2][3];
#pragma unroll
  for (int i = 0; i < 2; ++i)
#pragma unroll
    for (int j = 0; j < 3; ++j) acc[i][j] = (f32x4){0.f, 0.f, 0.f, 0.f};

  const u16* wbase = wt + (long)(nh * 192) * 1024;

  // W stage: 768 16B-chunks, 512 threads -> 1.5/thread
  auto stage_w = [&](int bufi, int k0) {
#pragma unroll
    for (int i = 0; i < 2; ++i) {
      int ci = i * 512 + t;
      if (ci < 768) {
        int row = ci >> 2, ch = ci & 3;              // local row 0..191
        gload_lds16(wbase + (long)row * 1024 + k0 + ((ch ^ ((row >> 1) & 3)) << 3),
                    &wl[bufi][0] + ci * 8);
      }
    }
  };

  auto xwrite = [&](int bufi, float4 a, float4 b2) {
    u16x4 o0, o1;
    o0[0] = f2b_fast(a.x); o0[1] = f2b_fast(a.y); o0[2] = f2b_fast(a.z); o0[3] = f2b_fast(a.w);
    o1[0] = f2b_fast(b2.x); o1[1] = f2b_fast(b2.y); o1[2] = f2b_fast(b2.z); o1[3] = f2b_fast(b2.w);
    *(u16x4*)(&xl[bufi][0] + xoff) = (sc8 & 1) ? o0 : o0;  // placeholder (replaced below)
  };

  // prologue: ks=0 written now; ks=1, ks=2 loads in flight
  {
    float4 a0 = *(const float4*)(xg);
    stage_w(0, 0);
    u16x4 o;
    o[0] = f2b_fast(a0.x); o[1] = f2b_fast(a0.y); o[2] = f2b_fast(a0.z); o[3] = f2b_fast(a0.w);
    *(u16x4*)(&xl[0][0] + xoff) = o;
  }
  float4 p0 = *(const float4*)(xg + 32);   // data for ks=1
  float4 p1 = *(const float4*)(xg + 64);   // data for ks=2
  __syncthreads();

  for (int ks = 0; ks < 32; ++ks) {
    int cur = ks & 1;
    float4 p2;
    if (ks + 3 < 32) p2 = *(const float4*)(xg + (ks + 3) * 32);  // 3-deep issue
    if (ks + 1 < 32) {
      stage_w(cur ^ 1, (ks + 1) * 32);
      u16x4 o;
      o[0] = f2b_fast(p0.x); o[1] = f2b_fast(p0.y); o[2] = f2b_fast(p0.z); o[3] = f2b_fast(p0.w);
      *(u16x4*)(&xl[cur ^ 1][0] + xoff) = o;
    }
    // compute from cur
    bf16x8 af[2], bfr[3];
#pragma unroll
    for (int i = 0; i < 2; ++i) {
      int row = wm * 32 + i * 16 + lr;
      af[i] = *(const bf16x8*)(&xl[cur][0] + row * 32 + ((lg ^ ((row >> 1) & 3)) << 3));
    }
#pragma unroll
    for (int j = 0; j < 3; ++j) {
      int row = wn * 48 + j * 16 + lr;
      bfr[j] = *(const bf16x8*)(&wl[cur][0] + row * 32 + ((lg ^ ((row >> 1) & 3)) << 3));
    }
#pragma unroll
    for (int i = 0; i < 2; ++i)
#pragma unroll
      for (int j = 0; j < 3; ++j)
        acc[i][j] = __builtin_amdgcn_mfma_f32_16x16x32_bf16(af[i], bfr[j], acc[i][j], 0, 0, 0);
    p0 = p1; p1 = p2;
    __syncthreads();
  }

  // epilogue: C layout row=(lane>>4)*4+reg, col=lane&15
#pragma unroll
  for (int i = 0; i < 2; ++i)
#pragma unroll
    for (int j = 0; j < 3; ++j)
#pragma unroll
      for (int r = 0; r < 4; ++r) {
        int m = mt * 64 + wm * 32 + i * 16 + lg * 4 + r;
        int col = nh * 192 + wn * 48 + j * 16 + lr;
        int z = col >> 7, cz = col & 127;
        u16 v = f2b(acc[i][j][r]);
        if (z == 0) qb[(long)m * 128 + cz] = v;
        else if (z == 1) kb[(long)m * 128 + cz] = v;
        else { int bb = m >> 12, sR = m & 4095; vt[(long)bb * 524288 + (long)cz * 4096 + sR] = v; }
      }
}

// flash attention v6 (reverted to R9 best-measured): uniform split-K chunks
// (8 key-tiles each); 576 blocks. 8-wave blocks share K/V staging, QBLK=128,
// KVBLK=64, fixed-max softmax, ones-MFMA row-sum, bf16 partials.
__global__ __launch_bounds__(512, 4) void k_attn(const u16* __restrict__ qb, const u16* __restrict__ kb,
                                                 const u16* __restrict__ vt, const int* __restrict__ kmask,
                                                 u16* __restrict__ po, float* __restrict__ pl) {
  const float SCALE_LOG2 = 0.08838834764831845f * 1.4426950408889634f;
  const float MFIX = 24.0f;
  int f = (NCHUNK - 1) - (int)blockIdx.x;  // long chunks (big qt2) first
  int b = blockIdx.y;
  // decode f -> (qt2, kc): nch(q) = ceil((q+1)/4) = (q+4)>>2
  int qt2 = 0, cum = 0;
  while (cum + ((qt2 + 4) >> 2) <= f) { cum += (qt2 + 4) >> 2; ++qt2; }
  int kc = f - cum;
  int ntile = 2 * qt2 + 2;
  int kt0 = kc * 8;
  int kt1 = min(kt0 + 8, ntile);

  int t = threadIdx.x, w = t >> 6, lane = t & 63;
  int lr = lane & 15, lg = lane >> 4, sw = lr & 7;
  int qrow0 = qt2 * 128 + w * 16;
  const u16* Q = qb + ((long)(b * SQ + qrow0)) * HQ;
  const u16* K = kb + (long)b * SQ * HQ;
  const u16* V = vt + (long)b * HQ * SQ;   // V^T: [128][SQ]
  const int* msk = kmask + b * SQ;

  __shared__ __align__(16) u16 Kl[2][64 * 128];   // 2 x 16 KB
  __shared__ __align__(16) u16 Vl[2][128 * 64];   // 2 x 16 KB
  __shared__ __align__(16) u16 plds[8][16 * 64];  // 16 KB, XOR-chunk layout

  bf16x8 aq[4];
#pragma unroll
  for (int c = 0; c < 4; ++c) aq[c] = *(const bf16x8*)(Q + lr * HQ + c * 32 + lg * 8);

  bf16x8 ones;
#pragma unroll
  for (int e = 0; e < 8; ++e) ones[e] = (short)0x3F80;

  f32x4 o[8];
#pragma unroll
  for (int n = 0; n < 8; ++n) o[n] = (f32x4){0.f, 0.f, 0.f, 0.f};
  f32x4 l_acc = (f32x4){0.f, 0.f, 0.f, 0.f};

  auto stage = [&](int bufi, int kb0) {
    const u16* Kg = K + (long)kb0 * HQ;
    const u16* Vg = V + kb0;
#pragma unroll
    for (int i = 0; i < 2; ++i) {
      int ci = w * 2 + i;
      int o16 = ci * 64 + lane;
      int row = o16 >> 4, ch = o16 & 15;
      gload_lds16(Kg + row * HQ + ((ch ^ (row & 7)) << 3), &Kl[bufi][ci * 512]);
    }
#pragma unroll
    for (int i = 0; i < 2; ++i) {
      int ci = w * 2 + i;
      int o16 = ci * 64 + lane;
      int row = o16 >> 3, ch = o16 & 7;
      gload_lds16(Vg + (long)row * SQ + ((ch ^ (row & 7)) << 3), &Vl[bufi][ci * 512]);
    }
  };

  stage(0, kt0 * 64);
  __syncthreads();

  u16* pw = &plds[w][0];
  for (int kt = kt0; kt < kt1; ++kt) {
    int cur = (kt - kt0) & 1;
    int kb0 = kt * 64;
    if (kt + 1 < kt1) stage(cur ^ 1, kb0 + 64);

    if (kb0 <= qrow0 + 15) {                 // wave-uniform: any valid keys?
      f32x4 s[4];
#pragma unroll
      for (int h = 0; h < 4; ++h) {
        f32x4 acc = (f32x4){0.f, 0.f, 0.f, 0.f};
        const u16* Kp = &Kl[cur][(h * 16 + lr) * 128];
#pragma unroll
        for (int c = 0; c < 4; ++c) {
          bf16x8 bk = *(const bf16x8*)(Kp + (((c * 4 + lg) ^ sw) << 3));
          acc = __builtin_amdgcn_mfma_f32_16x16x32_bf16(aq[c], bk, acc, 0, 0, 0);
        }
        s[h] = acc;
      }
      float mf[4];
#pragma unroll
      for (int h = 0; h < 4; ++h) mf[h] = (msk[kb0 + h * 16 + lr] != 0) ? 1.0f : 0.0f;
      bool needc = (kb0 + 63 > qrow0);       // tile crosses diagonal for this wave
#pragma unroll
      for (int r = 0; r < 4; ++r) {
        int row = lg * 4 + r;
        int qr = qrow0 + row;
#pragma unroll
        for (int h = 0; h < 4; ++h) {
          float p = __builtin_exp2f(fmaf(s[h][r], SCALE_LOG2, -MFIX)) * mf[h];
          if (needc) p = ((kb0 + h * 16 + lr) <= qr) ? p : 0.0f;
          int poff = row * 64 + ((((h * 2 + (lr >> 3)) ^ (row & 7))) << 3) + (lr & 7);
          pw[poff] = f2b_fast(p);
        }
      }
      bf16x8 ap0 = *(const bf16x8*)(pw + lr * 64 + ((lg ^ sw) << 3));
      bf16x8 ap1 = *(const bf16x8*)(pw + lr * 64 + (((4 + lg) ^ sw) << 3));
      l_acc = __builtin_amdgcn_mfma_f32_16x16x32_bf16(ap0, ones, l_acc, 0, 0, 0);
      l_acc = __builtin_amdgcn_mfma_f32_16x16x32_bf16(ap1, ones, l_acc, 0, 0, 0);
#pragma unroll
      for (int n = 0; n < 8; ++n) {
        const u16* Vp = &Vl[cur][(n * 16 + lr) * 64];
        bf16x8 bv0 = *(const bf16x8*)(Vp + ((lg ^ sw) << 3));
        bf16x8 bv1 = *(const bf16x8*)(Vp + (((4 + lg) ^ sw) << 3));
        o[n] = __builtin_amdgcn_mfma_f32_16x16x32_bf16(ap0, bv0, o[n], 0, 0, 0);
        o[n] = __builtin_amdgcn_mfma_f32_16x16x32_bf16(ap1, bv1, o[n], 0, 0, 0);
      }
    }
    __syncthreads();
  }

  // ---- write partials (bf16 O, f32 l)
  long p = (long)b * NCHUNK + f;
  u16* pob = po + p * 16384;  // [128][128] bf16
#pragma unroll
  for (int n = 0; n < 8; ++n)
#pragma unroll
    for (int r = 0; r < 4; ++r)
      pob[(w * 16 + lg * 4 + r) * 128 + n * 16 + lr] = f2b_fast(o[n][r]);
  if (lr == 0) {
#pragma unroll
    for (int r = 0; r < 4; ++r) pl[p * 128 + w * 16 + lg * 4 + r] = l_acc[r];
  }
}

// merge: out[b, qt2*128+row, :] = sum_i po[i] / sum_i pl[i]
__global__ __launch_bounds__(256) void k_merge(const u16* __restrict__ po, const float* __restrict__ pl,
                                               float* __restrict__ out) {
  int qt2 = blockIdx.x, b = blockIdx.y;
  int nch = (qt2 + 4) >> 2;
  int pre = 0;
  for (int q = 0; q < qt2; ++q) pre += (q + 4) >> 2;
  long pbase = (long)b * NCHUNK + pre;
  int t = threadIdx.x;
  int row = t >> 1, c0 = (t & 1) * 64;
  float l = 0.f;
  for (int i = 0; i < nch; ++i) l += pl[(pbase + i) * 128 + row];
  float inv = 1.0f / l;
  const u16* p0 = po + pbase * 16384 + row * 128 + c0;
  float* orow = out + ((long)(b * SQ + qt2 * 128 + row)) * HQ + c0;
#pragma unroll
  for (int j = 0; j < 64; j += 4) {
    float acc0 = 0.f, acc1 = 0.f, acc2 = 0.f, acc3 = 0.f;
    for (int i = 0; i < nch; ++i) {
      u16x4 v = *(const u16x4*)(p0 + (long)i * 16384 + j);
      acc0 += b2f(v[0]); acc1 += b2f(v[1]); acc2 += b2f(v[2]); acc3 += b2f(v[3]);
    }
    float4 r = {acc0 * inv, acc1 * inv, acc2 * inv, acc3 * inv};
    *(float4*)(orow + j) = r;
  }
}

extern "C" void kernel_launch(void* const* d_in, const int* in_sizes, int n_in,
                              void* d_out, int out_size, void* d_ws, size_t ws_size,
                              hipStream_t stream) {
  const float* x  = (const float*)d_in[0];
  const float* Wq = (const float*)d_in[1];
  const float* Wk = (const float*)d_in[2];
  const float* Wv = (const float*)d_in[3];
  const int* kmask = (const int*)d_in[4];
  char* ws = (char*)d_ws;
  u16* wt = (u16*)(ws + 33554432);            // 768 KB: Wt (dead after k_proj)
  u16* qb = (u16*)(ws + 34340864);            // 4 MB: Q bf16
  u16* kb = (u16*)(ws + 38535168);            // 4 MB: K bf16
  u16* vt = (u16*)(ws + 42729472);            // 4 MB: V^T bf16 [4][128][4096]
  u16* po = (u16*)ws;                         // 18.9 MB partial O (bf16)
  float* pl = (float*)(ws + 31195136);        // 295 KB partial l (po-region tail, unused)
  float* out = (float*)d_out;

  k_wt<<<1536, 256, 0, stream>>>(Wq, Wk, Wv, wt);
  k_proj<<<dim3(256, 2), 512, 0, stream>>>(x, wt, qb, kb, vt);
  k_attn<<<dim3(NCHUNK, 4), 512, 0, stream>>>(qb, kb, vt, kmask, po, pl);
  k_merge<<<dim3(32, 4), 256, 0, stream>>>(po, pl, out);
}